// Round 2
// baseline (102.625 us; speedup 1.0000x reference)
//
#include <hip/hip_runtime.h>
#include <cstdint>

#define IN_DIM   128
#define OUT_DIM  256
#define GRIDSZ   16
#define NROWS    32768
#define KDIM     4096          // 128 * 16 * 2
#define BM       128
#define NSTEPS   64            // K-tiles of 64

typedef unsigned short u16;
typedef __attribute__((ext_vector_type(8))) __bf16 bf16x8;
typedef __attribute__((ext_vector_type(4))) float  f32x4;

// ---------------------------------------------------------------------------
// Prep: repack fouriercoeffs (2,256,128,16) f32 -> Bpack bf16 [K/8][256][8]
// with k = i*32 + t*16 + g  (t: 0=cos, 1=sin; harmonic multiplier = g+1).
// ---------------------------------------------------------------------------
__global__ __launch_bounds__(256) void kan_prep(const float* __restrict__ C,
                                                u16* __restrict__ Bpack) {
    const int o = threadIdx.x;   // 0..255 output channel
    const int i = blockIdx.x;    // 0..127 input dim
    const int t = blockIdx.y;    // 0=cos, 1=sin
    const float* src = C + (((size_t)(t * OUT_DIM + o) * IN_DIM + i) * GRIDSZ);
    bf16x8 lo = {}, hi = {};
#pragma unroll
    for (int g = 0; g < 8; ++g) {
        lo[g] = (__bf16)src[g];
        hi[g] = (__bf16)src[8 + g];
    }
    const int ko = i * 4 + t * 2;       // k>>3
    bf16x8* dst = (bf16x8*)Bpack;
    dst[(size_t)ko * OUT_DIM + o]       = lo;   // g = 0..7
    dst[(size_t)(ko + 1) * OUT_DIM + o] = hi;   // g = 8..15
}

// ---------------------------------------------------------------------------
// Fused trig + bf16 MFMA GEMM. A generated in-kernel into LDS; B fragments
// loaded DIRECTLY from global (2 MB, L2-resident) into registers with a
// one-K-tile software prefetch. No global_load_lds, no Bsm.
// Tile: BM=128 rows x 128 cols per block, 4 waves of 64x64.
// ---------------------------------------------------------------------------
__global__ __launch_bounds__(256, 2) void kan_gemm(const float* __restrict__ x,
                                                   const u16* __restrict__ Bpack,
                                                   const float* __restrict__ bias,
                                                   float* __restrict__ out) {
    __shared__ __align__(16) u16 Asm[8 * BM * 8];  // [ko][row][e]  16 KB

    const int tid  = threadIdx.x;
    const int lane = tid & 63;
    const int wid  = tid >> 6;     // 0..3
    const int lrow = lane & 15;
    const int lk   = lane >> 4;    // 0..3 k-chunk
    const int wm   = wid >> 1;     // 0..1
    const int wn   = wid & 1;      // 0..1
    const int m0   = blockIdx.x * BM;
    const int n0   = blockIdx.y * 128;

    // trig mapping: thread -> (row, i-parity)
    const int tr  = tid >> 1;      // 0..127
    const int til = tid & 1;       // 0..1

    const f32x4 vzero = {0.f, 0.f, 0.f, 0.f};
    f32x4 acc[4][4];
#pragma unroll
    for (int a = 0; a < 4; ++a)
#pragma unroll
        for (int b = 0; b < 4; ++b) acc[a][b] = vzero;

    bf16x8* Av = (bf16x8*)Asm;
    const bf16x8* Bv = (const bf16x8*)Bpack;

    const float* xrow = x + (size_t)(m0 + tr) * IN_DIM + til;
    const int bcol = n0 + wn * 64 + lrow;   // + f*16 per fragment

    // prime B fragments for kt = 0
    bf16x8 bg[2][4];
#pragma unroll
    for (int ks = 0; ks < 2; ++ks)
#pragma unroll
        for (int f = 0; f < 4; ++f)
            bg[ks][f] = Bv[(size_t)(ks * 4 + lk) * OUT_DIM + bcol + f * 16];

    for (int kt = 0; kt < NSTEPS; ++kt) {
        __syncthreads();  // previous compute done reading Asm

        // ---- A tile: accurate sincos + angle-addition recurrence ----
        {
            const float xv = xrow[kt * 2];
            float s1, c1;
            sincosf(xv, &s1, &c1);
            bf16x8 qc0 = {}, qc1 = {}, qs0 = {}, qs1 = {};
            float cg = c1, sg = s1;
            qc0[0] = (__bf16)cg;
            qs0[0] = (__bf16)sg;
#pragma unroll
            for (int g = 1; g < 16; ++g) {
                const float cn = c1 * cg - s1 * sg;
                const float sn = s1 * cg + c1 * sg;
                cg = cn; sg = sn;
                if (g < 8) { qc0[g] = (__bf16)cg;     qs0[g] = (__bf16)sg; }
                else       { qc1[g - 8] = (__bf16)cg; qs1[g - 8] = (__bf16)sg; }
            }
            const int kob = til * 4;   // local ko = til*4 + t*2 + (g>>3)
            Av[(kob + 0) * BM + tr] = qc0;
            Av[(kob + 1) * BM + tr] = qc1;
            Av[(kob + 2) * BM + tr] = qs0;
            Av[(kob + 3) * BM + tr] = qs1;
        }

        __syncthreads();  // Asm staged

        // ---- prefetch next tile's B fragments (L2-resident) ----
        bf16x8 bgn[2][4];
        const int ktn = (kt + 1 < NSTEPS) ? (kt + 1) : 0;
#pragma unroll
        for (int ks = 0; ks < 2; ++ks)
#pragma unroll
            for (int f = 0; f < 4; ++f)
                bgn[ks][f] = Bv[(size_t)(ktn * 8 + ks * 4 + lk) * OUT_DIM + bcol + f * 16];

        // ---- compute: 2 x (4 ds_read_b128 + 16 MFMA) ----
#pragma unroll
        for (int ks = 0; ks < 2; ++ks) {
            const int kq = ks * 4 + lk;
            bf16x8 af[4];
#pragma unroll
            for (int f = 0; f < 4; ++f)
                af[f] = Av[kq * BM + wm * 64 + f * 16 + lrow];
#pragma unroll
            for (int fm = 0; fm < 4; ++fm)
#pragma unroll
                for (int fn = 0; fn < 4; ++fn)
                    acc[fm][fn] = __builtin_amdgcn_mfma_f32_16x16x32_bf16(
                        af[fm], bg[ks][fn], acc[fm][fn], 0, 0, 0);
        }

#pragma unroll
        for (int ks = 0; ks < 2; ++ks)
#pragma unroll
            for (int f = 0; f < 4; ++f)
                bg[ks][f] = bgn[ks][f];
    }

    // ---- epilogue: C[row][col], row=(lane>>4)*4+j, col=lane&15 ----
#pragma unroll
    for (int fn = 0; fn < 4; ++fn) {
        const int col = n0 + wn * 64 + fn * 16 + lrow;
        const float bv = bias[col];
#pragma unroll
        for (int fm = 0; fm < 4; ++fm) {
            const int r0 = m0 + wm * 64 + fm * 16 + lk * 4;
            float* op = out + (size_t)r0 * OUT_DIM + col;
#pragma unroll
            for (int j = 0; j < 4; ++j)
                op[(size_t)j * OUT_DIM] = acc[fm][fn][j] + bv;
        }
    }
}

extern "C" void kernel_launch(void* const* d_in, const int* in_sizes, int n_in,
                              void* d_out, int out_size, void* d_ws, size_t ws_size,
                              hipStream_t stream) {
    const float* x    = (const float*)d_in[0];   // (32768, 128) f32
    const float* fc   = (const float*)d_in[1];   // (2, 256, 128, 16) f32
    const float* bias = (const float*)d_in[2];   // (1, 256) f32
    float* out        = (float*)d_out;           // (32768, 256) f32
    u16* Bpack        = (u16*)d_ws;              // 4096*256*2 B = 2 MB scratch

    kan_prep<<<dim3(IN_DIM, 2), OUT_DIM, 0, stream>>>(fc, Bpack);
    kan_gemm<<<dim3(NROWS / BM, OUT_DIM / 128), 256, 0, stream>>>(x, Bpack, bias, out);
}

// Round 3
// 84.151 us; speedup vs baseline: 1.2195x; 1.2195x over previous
//
#include <hip/hip_runtime.h>
#include <cstdint>

#define IN_DIM   128
#define OUT_DIM  256
#define GRIDSZ   16
#define NROWS    32768
#define BM       128
#define BK       128           // 4 i-values per K-step
#define NSTEPS   32            // K = 4096 = 32 * 128

typedef unsigned short u16;
typedef __attribute__((ext_vector_type(8))) __bf16 bf16x8;
typedef __attribute__((ext_vector_type(4))) float  f32x4;

// ---------------------------------------------------------------------------
// Prep: repack fouriercoeffs (2,256,128,16) f32 -> Bpack bf16 [K/8][256][8]
// with k = i*32 + t*16 + g  (t: 0=cos, 1=sin; slot g holds harmonic g+1).
// ---------------------------------------------------------------------------
__global__ __launch_bounds__(256) void kan_prep(const float* __restrict__ C,
                                                u16* __restrict__ Bpack) {
    const int o = threadIdx.x;   // 0..255 output channel
    const int i = blockIdx.x;    // 0..127 input dim
    const int t = blockIdx.y;    // 0=cos, 1=sin
    const float* src = C + (((size_t)(t * OUT_DIM + o) * IN_DIM + i) * GRIDSZ);
    bf16x8 lo = {}, hi = {};
#pragma unroll
    for (int g = 0; g < 8; ++g) {
        lo[g] = (__bf16)src[g];
        hi[g] = (__bf16)src[8 + g];
    }
    const int ko = i * 4 + t * 2;       // k>>3
    bf16x8* dst = (bf16x8*)Bpack;
    dst[(size_t)ko * OUT_DIM + o]       = lo;   // g = 0..7
    dst[(size_t)(ko + 1) * OUT_DIM + o] = hi;   // g = 8..15
}

// ---------------------------------------------------------------------------
// Fused trig + bf16 MFMA GEMM, v3:
//  - BM=128 x BN=256 (full N) per block: trig for each (row,i) computed ONCE.
//  - 512 threads = 8 waves (2m x 4n), wave tile 64x64, 4x4 frags 16x16x32.
//  - A double-buffered in LDS, ONE barrier per K-step: gen(kt+1) VALU stream
//    interleaves with MFMA(kt) in the same barrier region.
//  - Chebyshev harmonic recurrence (2 FMA/harmonic), __sincosf seed.
//  - B fragments loaded directly from L2-resident Bpack, 1-step prefetch.
// ---------------------------------------------------------------------------
__global__ __launch_bounds__(512, 2) void kan_gemm(const float* __restrict__ x,
                                                   const u16* __restrict__ Bpack,
                                                   const float* __restrict__ bias,
                                                   float* __restrict__ out) {
    __shared__ __align__(16) u16 Asm[2][16 * BM * 8];   // 2 x 32 KB

    const int tid  = threadIdx.x;
    const int lane = tid & 63;
    const int wid  = tid >> 6;       // 0..7
    const int lrow = lane & 15;
    const int lk   = lane >> 4;      // 0..3  k-chunk
    const int wm   = wid >> 2;       // 0..1  row block
    const int wn   = wid & 3;        // 0..3  col block
    const int m0   = blockIdx.x * BM;

    // trig task mapping: thread -> (row tr, i-sub til), i = kt*4 + til
    const int tr  = tid >> 2;        // 0..127
    const int til = tid & 3;         // 0..3

    const f32x4 vzero = {0.f, 0.f, 0.f, 0.f};
    f32x4 acc[4][4];
#pragma unroll
    for (int a = 0; a < 4; ++a)
#pragma unroll
        for (int b = 0; b < 4; ++b) acc[a][b] = vzero;

    const bf16x8* Bv = (const bf16x8*)Bpack;
    bf16x8* Av0 = (bf16x8*)Asm[0];
    bf16x8* Av1 = (bf16x8*)Asm[1];

    const float* xrow = x + (size_t)(m0 + tr) * IN_DIM + til;
    const int bcol = wn * 64 + lrow;           // + f*16 per fragment

    // ---- harmonic generator: writes 4 bf16x8 rows into Av ----
    auto gen = [&](bf16x8* Av, float xv) {
        float s1, c1;
        __sincosf(xv, &s1, &c1);
        const float t2 = 2.f * c1;
        bf16x8 qc0 = {}, qc1 = {}, qs0 = {}, qs1 = {};
        float cp = c1, sp = s1;                    // harmonic 1
        float cc = t2 * c1 - 1.f, sc = t2 * s1;    // harmonic 2
        qc0[0] = (__bf16)cp;  qs0[0] = (__bf16)sp;
        qc0[1] = (__bf16)cc;  qs0[1] = (__bf16)sc;
#pragma unroll
        for (int g = 3; g <= 16; ++g) {            // Chebyshev: 2 FMA each
            const float cn = t2 * cc - cp;
            const float sn = t2 * sc - sp;
            cp = cc; sp = sc; cc = cn; sc = sn;
            const int idx = g - 1;                 // slot = harmonic-1
            if (idx < 8) { qc0[idx] = (__bf16)cc;      qs0[idx] = (__bf16)sc; }
            else         { qc1[idx - 8] = (__bf16)cc;  qs1[idx - 8] = (__bf16)sc; }
        }
        const int kob = til * 4;   // local ko = til*4 + t*2 + (g>>3)
        Av[(kob + 0) * BM + tr] = qc0;
        Av[(kob + 1) * BM + tr] = qc1;
        Av[(kob + 2) * BM + tr] = qs0;
        Av[(kob + 3) * BM + tr] = qs1;
    };

    // prime B fragments for kt=0, ks=0  (kq = lk)
    bf16x8 bg[4];
#pragma unroll
    for (int f = 0; f < 4; ++f)
        bg[f] = Bv[(size_t)lk * OUT_DIM + bcol + f * 16];

    // prologue: gen tile 0, prefetch x for tile 1
    float xn = xrow[4];
    gen(Av0, xrow[0]);
    __syncthreads();

    for (int kt = 0; kt < NSTEPS; ++kt) {
        bf16x8* Avc = (kt & 1) ? Av1 : Av0;
        bf16x8* Avn = (kt & 1) ? Av0 : Av1;

        // generate next A tile (VALU) — interleaves with this tile's MFMAs
        if (kt + 1 < NSTEPS) {
            gen(Avn, xn);
            xn = xrow[((kt + 2) & (NSTEPS - 1)) * 4];
        }

#pragma unroll
        for (int ks = 0; ks < 4; ++ks) {
            // prefetch next ks's B fragments (wraps harmlessly at the end)
            const int ktn = (ks == 3) ? ((kt + 1) & (NSTEPS - 1)) : kt;
            const int ksn = (ks + 1) & 3;
            const size_t kqn = (size_t)(ktn * 16 + ksn * 4 + lk);
            bf16x8 bgn[4];
#pragma unroll
            for (int f = 0; f < 4; ++f)
                bgn[f] = Bv[kqn * OUT_DIM + bcol + f * 16];

            const int kq = ks * 4 + lk;
            bf16x8 af[4];
#pragma unroll
            for (int f = 0; f < 4; ++f)
                af[f] = Avc[kq * BM + wm * 64 + f * 16 + lrow];
#pragma unroll
            for (int fm = 0; fm < 4; ++fm)
#pragma unroll
                for (int fn = 0; fn < 4; ++fn)
                    acc[fm][fn] = __builtin_amdgcn_mfma_f32_16x16x32_bf16(
                        af[fm], bg[fn], acc[fm][fn], 0, 0, 0);
#pragma unroll
            for (int f = 0; f < 4; ++f) bg[f] = bgn[f];
        }
        __syncthreads();
    }

    // ---- epilogue: C[row][col], row=(lane>>4)*4+j, col=lane&15 ----
#pragma unroll
    for (int fn = 0; fn < 4; ++fn) {
        const int col = wn * 64 + fn * 16 + lrow;
        const float bv = bias[col];
#pragma unroll
        for (int fm = 0; fm < 4; ++fm) {
            const int r0 = m0 + wm * 64 + fm * 16 + lk * 4;
            float* op = out + (size_t)r0 * OUT_DIM + col;
#pragma unroll
            for (int j = 0; j < 4; ++j)
                op[(size_t)j * OUT_DIM] = acc[fm][fn][j] + bv;
        }
    }
}

extern "C" void kernel_launch(void* const* d_in, const int* in_sizes, int n_in,
                              void* d_out, int out_size, void* d_ws, size_t ws_size,
                              hipStream_t stream) {
    const float* x    = (const float*)d_in[0];   // (32768, 128) f32
    const float* fc   = (const float*)d_in[1];   // (2, 256, 128, 16) f32
    const float* bias = (const float*)d_in[2];   // (1, 256) f32
    float* out        = (float*)d_out;           // (32768, 256) f32
    u16* Bpack        = (u16*)d_ws;              // 4096*256*2 B = 2 MB scratch

    kan_prep<<<dim3(IN_DIM, 2), OUT_DIM, 0, stream>>>(fc, Bpack);
    kan_gemm<<<dim3(NROWS / BM), 512, 0, stream>>>(x, Bpack, bias, out);
}

// Round 5
// 80.148 us; speedup vs baseline: 1.2804x; 1.0500x over previous
//
#include <hip/hip_runtime.h>
#include <cstdint>

#define IN_DIM   128
#define OUT_DIM  256
#define NROWS    32768
#define BM       64            // rows per block
#define NSTEPS   16            // K = 4096 = 16 * 256 (BK=256: 8 i-values/step)
#define STR      65            // bf16x8 row stride (64 + 1 pad)

typedef unsigned short u16;
typedef __attribute__((ext_vector_type(8))) __bf16 bf16x8;
typedef __attribute__((ext_vector_type(4))) float  f32x4;

// ---------------------------------------------------------------------------
// Prep: repack fouriercoeffs (2,256,128,16) f32 -> Bpack bf16 [K/8][256][8]
// with k = i*32 + t*16 + g  (t: 0=cos, 1=sin; slot g holds harmonic g+1).
// ---------------------------------------------------------------------------
__global__ __launch_bounds__(256) void kan_prep(const float* __restrict__ C,
                                                u16* __restrict__ Bpack) {
    const int o = threadIdx.x;   // 0..255 output channel
    const int i = blockIdx.x;    // 0..127 input dim
    const int t = blockIdx.y;    // 0=cos, 1=sin
    const float* src = C + (((size_t)(t * OUT_DIM + o) * IN_DIM + i) * 16);
    bf16x8 lo = {}, hi = {};
#pragma unroll
    for (int g = 0; g < 8; ++g) {
        lo[g] = (__bf16)src[g];
        hi[g] = (__bf16)src[8 + g];
    }
    const int ko = i * 4 + t * 2;       // k>>3
    bf16x8* dst = (bf16x8*)Bpack;
    dst[(size_t)ko * OUT_DIM + o]       = lo;   // g = 0..7
    dst[(size_t)(ko + 1) * OUT_DIM + o] = hi;   // g = 8..15
}

// ---------------------------------------------------------------------------
// Fused trig + bf16 MFMA GEMM, v5: v3's PROVEN structure (1 barrier/K-step,
// double-buffered A, direct epilogue, full-16-harmonic gen per thread),
// re-shaped for occupancy:
//  - BM=64, BK=256, 512 threads = 8 waves, wave tile 64x32 (wn=wid).
//    No wm-duplication of B reads (B L2 traffic halved per output).
//  - grid 512 blocks; __launch_bounds__(512,4) -> 2 blocks/CU = 4 waves/SIMD
//    (v3 was 2/SIMD; this is the measured latency-hiding gap).
//  - LDS 2 x 32.5 KB per block; STR=65 pad spreads bank groups.
// ---------------------------------------------------------------------------
__global__ __launch_bounds__(512, 4) void kan_gemm(const float* __restrict__ x,
                                                   const u16* __restrict__ Bpack,
                                                   const float* __restrict__ bias,
                                                   float* __restrict__ out) {
    __shared__ __align__(16) u16 Asm[2][32 * STR * 8];   // 2 x 33280 B

    const int tid  = threadIdx.x;
    const int lane = tid & 63;
    const int wid  = tid >> 6;       // 0..7
    const int lrow = lane & 15;
    const int lk   = lane >> 4;      // 0..3  k-chunk
    const int wn   = wid;            // col block: 32 cols each
    const int m0   = blockIdx.x * BM;

    // trig task mapping: thread -> (row tr, i-sub til), i = kt*8 + til
    const int tr  = tid >> 3;        // 0..63
    const int til = tid & 7;         // 0..7

    const f32x4 vzero = {0.f, 0.f, 0.f, 0.f};
    f32x4 acc[4][2];
#pragma unroll
    for (int a = 0; a < 4; ++a)
#pragma unroll
        for (int b = 0; b < 2; ++b) acc[a][b] = vzero;

    const bf16x8* Bv = (const bf16x8*)Bpack;
    bf16x8* Av0 = (bf16x8*)Asm[0];
    bf16x8* Av1 = (bf16x8*)Asm[1];

    const float* xrow = x + (size_t)(m0 + tr) * IN_DIM + til;
    const int bcol = wn * 32 + lrow;           // + f*16 per fragment

    // ---- harmonic generator (v3 verbatim, stride STR): 4 ds_write_b128 ----
    auto gen = [&](bf16x8* Av, float xv) {
        float s1, c1;
        __sincosf(xv, &s1, &c1);
        const float t2 = 2.f * c1;
        bf16x8 qc0 = {}, qc1 = {}, qs0 = {}, qs1 = {};
        float cp = c1, sp = s1;                    // harmonic 1
        float cc = t2 * c1 - 1.f, sc = t2 * s1;    // harmonic 2
        qc0[0] = (__bf16)cp;  qs0[0] = (__bf16)sp;
        qc0[1] = (__bf16)cc;  qs0[1] = (__bf16)sc;
#pragma unroll
        for (int g = 3; g <= 16; ++g) {            // Chebyshev: 2 FMA each
            const float cn = t2 * cc - cp;
            const float sn = t2 * sc - sp;
            cp = cc; sp = sc; cc = cn; sc = sn;
            const int idx = g - 1;                 // slot = harmonic-1
            if (idx < 8) { qc0[idx] = (__bf16)cc;      qs0[idx] = (__bf16)sc; }
            else         { qc1[idx - 8] = (__bf16)cc;  qs1[idx - 8] = (__bf16)sc; }
        }
        const int kob = til * 4;   // local ko = til*4 + t*2 + (g>>3)
        Av[(kob + 0) * STR + tr] = qc0;
        Av[(kob + 1) * STR + tr] = qc1;
        Av[(kob + 2) * STR + tr] = qs0;
        Av[(kob + 3) * STR + tr] = qs1;
    };

    // prime B fragments for kt=0, ks=0  (ko_global = lk)
    bf16x8 bg[2];
#pragma unroll
    for (int f = 0; f < 2; ++f)
        bg[f] = Bv[(size_t)lk * OUT_DIM + bcol + f * 16];

    // prologue: gen tile 0, prefetch x for tile 1
    float xn = xrow[8];
    gen(Av0, xrow[0]);
    __syncthreads();

    for (int kt = 0; kt < NSTEPS; ++kt) {
        bf16x8* Avc = (kt & 1) ? Av1 : Av0;
        bf16x8* Avn = (kt & 1) ? Av0 : Av1;

        // generate next A tile (VALU) — interleaves with this tile's MFMAs
        if (kt + 1 < NSTEPS) {
            gen(Avn, xn);
            xn = xrow[((kt + 2) & (NSTEPS - 1)) * 8];
        }

#pragma unroll
        for (int ks = 0; ks < 8; ++ks) {
            // prefetch next ks's B fragments (wraps harmlessly at the end)
            const int ktn = (ks == 7) ? ((kt + 1) & (NSTEPS - 1)) : kt;
            const int ksn = (ks + 1) & 7;
            const size_t kqn = (size_t)(ktn * 32 + ksn * 4 + lk);
            bf16x8 bgn[2];
#pragma unroll
            for (int f = 0; f < 2; ++f)
                bgn[f] = Bv[kqn * OUT_DIM + bcol + f * 16];

            const int kq = ks * 4 + lk;
            bf16x8 af[4];
#pragma unroll
            for (int f = 0; f < 4; ++f)
                af[f] = Avc[kq * STR + f * 16 + lrow];
#pragma unroll
            for (int fm = 0; fm < 4; ++fm)
#pragma unroll
                for (int fn = 0; fn < 2; ++fn)
                    acc[fm][fn] = __builtin_amdgcn_mfma_f32_16x16x32_bf16(
                        af[fm], bg[fn], acc[fm][fn], 0, 0, 0);
#pragma unroll
            for (int f = 0; f < 2; ++f) bg[f] = bgn[f];
        }
        __syncthreads();
    }

    // ---- epilogue: C[row][col], row=(lane>>4)*4+j, col=lane&15 ----
#pragma unroll
    for (int fn = 0; fn < 2; ++fn) {
        const int col = wn * 32 + fn * 16 + lrow;
        const float bv = bias[col];
#pragma unroll
        for (int fm = 0; fm < 4; ++fm) {
            const int r0 = m0 + fm * 16 + lk * 4;
            float* op = out + (size_t)r0 * OUT_DIM + col;
#pragma unroll
            for (int j = 0; j < 4; ++j)
                op[(size_t)j * OUT_DIM] = acc[fm][fn][j] + bv;
        }
    }
}

extern "C" void kernel_launch(void* const* d_in, const int* in_sizes, int n_in,
                              void* d_out, int out_size, void* d_ws, size_t ws_size,
                              hipStream_t stream) {
    const float* x    = (const float*)d_in[0];   // (32768, 128) f32
    const float* fc   = (const float*)d_in[1];   // (2, 256, 128, 16) f32
    const float* bias = (const float*)d_in[2];   // (1, 256) f32
    float* out        = (float*)d_out;           // (32768, 256) f32
    u16* Bpack        = (u16*)d_ws;              // 4096*256*2 B = 2 MB scratch

    kan_prep<<<dim3(IN_DIM, 2), OUT_DIM, 0, stream>>>(fc, Bpack);
    kan_gemm<<<dim3(NROWS / BM), 512, 0, stream>>>(x, Bpack, bias, out);
}